// Round 1
// baseline (153.266 us; speedup 1.0000x reference)
//
#include <hip/hip_runtime.h>

// Committee vote histogram:
//   logits[m,b,c] = x[b,:] . W[m,:,c] + bias[m,c]
//   votes[m,b]    = argmax_c logits
//   out[b,c]      = #{ m : votes[m,b] == c }   (float32)
//
// B=65536, D=512, M=16, C=10.
// Strategy: block = 1024 threads (16 waves), 64 rows of x per block,
// one model per wave (wave-uniform -> W via scalar loads), x tile staged
// in LDS transposed so the FMA inner loop is ds_read_b128 + 40 v_fma_f32.

#define NB_ROWS 64
#define DDIM    512
#define NCLS    10
#define NMOD    16
#define KCHUNK  64

__global__ __launch_bounds__(1024, 2)
void committee_kernel(const float* __restrict__ x,
                      const float* __restrict__ W,
                      const float* __restrict__ bias,
                      float* __restrict__ out)
{
    // Transposed x tile: xs[kq][row] holds x[row][k0 + 4*kq .. +3].
    // Odd float4 leading stride (65) -> conflict-free b128 reads & writes.
    __shared__ float4 xs[16][65];
    __shared__ int ihist[NB_ROWS * NCLS];

    const int tid  = threadIdx.x;
    const int row0 = blockIdx.x * NB_ROWS;

    if (tid < NB_ROWS * NCLS) ihist[tid] = 0;

    const int m    = __builtin_amdgcn_readfirstlane(tid >> 6);  // wave id = model
    const int lane = tid & 63;                                  // row within tile

    const float* wp = W + (size_t)m * DDIM * NCLS;

    float acc[NCLS];
#pragma unroll
    for (int c = 0; c < NCLS; ++c) acc[c] = bias[m * NCLS + c];

    // staging mapping: thread t loads x[row0 + t/16][k0 + (t%16)*4 .. +3]
    const int srow = tid >> 4;   // 0..63
    const int skq  = tid & 15;   // 0..15

    for (int k0 = 0; k0 < DDIM; k0 += KCHUNK) {
        __syncthreads();  // protect xs from previous iteration's readers
        const float4 v = *reinterpret_cast<const float4*>(
            &x[(size_t)(row0 + srow) * DDIM + k0 + (skq << 2)]);
        xs[skq][srow] = v;
        __syncthreads();

#pragma unroll
        for (int kq = 0; kq < 16; ++kq) {
            const float4 xv = xs[kq][lane];
            const float xarr[4] = {xv.x, xv.y, xv.z, xv.w};
            // W chunk for this wave's model: wave-uniform -> s_load
            const float* wk = wp + (size_t)(k0 + (kq << 2)) * NCLS;
#pragma unroll
            for (int j = 0; j < 4; ++j) {
                const float xj = xarr[j];
#pragma unroll
                for (int c = 0; c < NCLS; ++c)
                    acc[c] = fmaf(xj, wk[j * NCLS + c], acc[c]);
            }
        }
    }

    // argmax with first-occurrence-of-max semantics (strict >)
    int best = 0;
    float bv = acc[0];
#pragma unroll
    for (int c = 1; c < NCLS; ++c) {
        if (acc[c] > bv) { bv = acc[c]; best = c; }
    }

    atomicAdd(&ihist[lane * NCLS + best], 1);
    __syncthreads();

    if (tid < NB_ROWS * NCLS) {
        out[(size_t)row0 * NCLS + tid] = (float)ihist[tid];
    }
}

extern "C" void kernel_launch(void* const* d_in, const int* in_sizes, int n_in,
                              void* d_out, int out_size, void* d_ws, size_t ws_size,
                              hipStream_t stream) {
    const float* x  = (const float*)d_in[0];   // [65536, 512]
    const float* W  = (const float*)d_in[1];   // [16, 512, 10]
    const float* b  = (const float*)d_in[2];   // [16, 10]
    float* out      = (float*)d_out;           // [65536, 10]

    const int nblocks = 65536 / NB_ROWS;       // 1024
    committee_kernel<<<nblocks, 1024, 0, stream>>>(x, W, b, out);
}